// Round 13
// baseline (446.545 us; speedup 1.0000x reference)
//
#include <hip/hip_runtime.h>
#include <hip/hip_fp16.h>

// Problem constants (from reference)
#define NN  100000   // nodes
#define FIN 128      // in features
#define HID 256      // hidden
#define NE  600000   // edges
#define FEPS 1e-12f

// ---------------------------------------------------------------------------
// Workspace layout:
//  Path A (~82.3 MB): Wt[256*256]f | xh[NN*FIN]h | agg[NN*FIN]f | cnt|cur|
//                     off|col | g|r | bsum
//  Path B (~31.1 MB): same minus agg (fused layer1, R9 structure)
//  Path C: minus xh too (fp32 fused fallback)
// Evidence log:
//  - R5: bf16 FEATURES fail precision (1/||z|| amplification); fp16 OK
//    (R9 absmax 0.0156 vs thr 0.0327). ws_size >= 31.1 MB.
//  - R6: wave-per-node gather REGRESSED. R7/R8: occupancy lever exhausted
//    (32 waves/CU, 291 us). R9: bytes not the limit (fp16: FETCH 170->100 MB,
//    time ~same). R10: divergent __shfl broken. R11: LDS fp32 atomics 3x
//    slow (CAS codegen). R12: 8-wide guarded batch neutral + scratch spill
//    (WRITE_SIZE 1.6->14 MB) => round count not the limit either.
//  - Remaining theory: block barrier couples 64 nodes; max-degree node gates
//    1024 threads. R13: split gather (barrier-free, global agg) + streaming
//    GEMM, ws-gated with fallback to R9 fused.
// ---------------------------------------------------------------------------

__device__ __forceinline__ int clampN(int v) {
    return ((unsigned)v < (unsigned)NN) ? v : 0;
}
// int64 vs int32 edge_index: little-endian int64 (<2^31) => odd words all 0.
__device__ __forceinline__ int detect4(const int* ei) {
    return ((ei[1] | ei[3] | ei[5] | ei[7]) == 0) ? 1 : 0;
}
__device__ __forceinline__ int ld_src(const int* ei, int e, int f) {
    return f ? ei[2 * e] : ei[e];
}
__device__ __forceinline__ int ld_dst(const int* ei, int e, int f) {
    return f ? ei[2 * (NE + e)] : ei[NE + e];
}

// ---------------------------------------------------------------------------
// Setup (fused): blocks [0,256) weight transpose; [256,256+ncv) x->fp16;
// [256+ncv, ...) in-degree count (cnt pre-zeroed by memset).
// ---------------------------------------------------------------------------
__global__ __launch_bounds__(256) void setup_kernel(
    const int* __restrict__ ei,
    const float* __restrict__ x,
    const float* __restrict__ W1l, const float* __restrict__ W1r,
    float* __restrict__ Wt, __half* __restrict__ xh,
    int* __restrict__ cnt, int ncv)
{
    int b = blockIdx.x;
    int t = threadIdx.x;
    if (b < 256) {
        int k2 = b;
        float v = (k2 < FIN) ? W1l[(size_t)t * FIN + k2]
                             : W1r[(size_t)t * FIN + (k2 - FIN)];
        Wt[(size_t)k2 * HID + t] = v;
    } else if (b < 256 + ncv) {
        int idx = (b - 256) * 256 + t;           // 8-float group
        if (idx < NN * FIN / 8) {
            const float4* px = (const float4*)(x + (size_t)idx * 8);
            float4 v0 = px[0], v1 = px[1];
            __half2 h0 = __float22half2_rn(make_float2(v0.x, v0.y));
            __half2 h1 = __float22half2_rn(make_float2(v0.z, v0.w));
            __half2 h2 = __float22half2_rn(make_float2(v1.x, v1.y));
            __half2 h3 = __float22half2_rn(make_float2(v1.z, v1.w));
            uint4 u;
            u.x = __builtin_bit_cast(unsigned, h0);
            u.y = __builtin_bit_cast(unsigned, h1);
            u.z = __builtin_bit_cast(unsigned, h2);
            u.w = __builtin_bit_cast(unsigned, h3);
            ((uint4*)xh)[idx] = u;
        }
    } else {
        int e = (b - 256 - ncv) * 256 + t;
        if (e < NE) {
            int f = detect4(ei);
            atomicAdd(cnt + clampN(ld_dst(ei, e, f)), 1);
        }
    }
}

// 3-phase parallel exclusive scan of cnt[NN] -> off[NN+1]
__global__ __launch_bounds__(1024) void scan_a_kernel(
    const int* __restrict__ cnt, int* __restrict__ off, int* __restrict__ bsum)
{
    __shared__ int sm[1024];
    int t = threadIdx.x;
    int idx = blockIdx.x * 1024 + t;
    int v = (idx < NN) ? cnt[idx] : 0;
    sm[t] = v;
    __syncthreads();
    for (int d = 1; d < 1024; d <<= 1) {
        int w = (t >= d) ? sm[t - d] : 0;
        __syncthreads();
        sm[t] += w;
        __syncthreads();
    }
    if (idx < NN) off[idx] = sm[t] - v;
    if (t == 1023) bsum[blockIdx.x] = sm[1023];
}
__global__ __launch_bounds__(128) void scan_b_kernel(
    int* __restrict__ bsum, int* __restrict__ off, int nblocks)
{
    __shared__ int sm[128];
    int t = threadIdx.x;
    int v = (t < nblocks) ? bsum[t] : 0;
    sm[t] = v;
    __syncthreads();
    for (int d = 1; d < 128; d <<= 1) {
        int w = (t >= d) ? sm[t - d] : 0;
        __syncthreads();
        sm[t] += w;
        __syncthreads();
    }
    if (t < nblocks) bsum[t] = sm[t] - v;
    if (t == 0) off[NN] = NE;
}
__global__ __launch_bounds__(1024) void scan_c_kernel(
    const int* __restrict__ bsum, int* __restrict__ off)
{
    int idx = blockIdx.x * 1024 + threadIdx.x;
    if (idx < NN) off[idx] += bsum[blockIdx.x];
}

// place src ids into CSR slots
__global__ __launch_bounds__(256) void fill_kernel(
    const int* __restrict__ ei,
    const int* __restrict__ off, int* __restrict__ cur, int* __restrict__ col)
{
    int e = blockIdx.x * 256 + threadIdx.x;
    if (e >= NE) return;
    int f = detect4(ei);
    int src = clampN(ld_src(ei, e, f));
    int dst = clampN(ld_dst(ei, e, f));
    int p = atomicAdd(cur + dst, 1);
    col[off[dst] + p] = src;
}

// ---------------------------------------------------------------------------
// Path A, stage 1: barrier-free gather. 1 thread per (node, 16B fp16 chunk);
// R9's 4-wide independent-load loop; mean written to global agg (fp32).
// No LDS, no __syncthreads: a high-degree straggler holds only its own wave.
// ---------------------------------------------------------------------------
__global__ __launch_bounds__(256) void gather_kernel(
    const int* __restrict__ off, const int* __restrict__ col,
    const __half* __restrict__ xh, float* __restrict__ agg)
{
    int idx = blockIdx.x * 256 + threadIdx.x;
    if (idx >= NN * 16) return;
    int n     = idx >> 4;
    int ft    = idx & 15;
    int fbase = ft * 8;

    float a[8];
#pragma unroll
    for (int i = 0; i < 8; ++i) a[i] = 0.0f;

    int s0 = off[n], s1 = off[n + 1];
    int i = s0;
    for (; i + 3 < s1; i += 4) {            // 4 independent 16B loads
        int c0 = clampN(col[i]);
        int c1 = clampN(col[i + 1]);
        int c2 = clampN(col[i + 2]);
        int c3 = clampN(col[i + 3]);
        uint4 v0 = *(const uint4*)(xh + (size_t)c0 * FIN + fbase);
        uint4 v1 = *(const uint4*)(xh + (size_t)c1 * FIN + fbase);
        uint4 v2 = *(const uint4*)(xh + (size_t)c2 * FIN + fbase);
        uint4 v3 = *(const uint4*)(xh + (size_t)c3 * FIN + fbase);
#pragma unroll
        for (int u = 0; u < 4; ++u) {
            float2 f0 = __half22float2(__builtin_bit_cast(__half2, (&v0.x)[u]));
            float2 f1 = __half22float2(__builtin_bit_cast(__half2, (&v1.x)[u]));
            float2 f2 = __half22float2(__builtin_bit_cast(__half2, (&v2.x)[u]));
            float2 f3 = __half22float2(__builtin_bit_cast(__half2, (&v3.x)[u]));
            a[2 * u]     += (f0.x + f1.x) + (f2.x + f3.x);
            a[2 * u + 1] += (f0.y + f1.y) + (f2.y + f3.y);
        }
    }
    for (; i < s1; ++i) {
        int c0 = clampN(col[i]);
        uint4 v0 = *(const uint4*)(xh + (size_t)c0 * FIN + fbase);
#pragma unroll
        for (int u = 0; u < 4; ++u) {
            float2 f0 = __half22float2(__builtin_bit_cast(__half2, (&v0.x)[u]));
            a[2 * u]     += f0.x;
            a[2 * u + 1] += f0.y;
        }
    }
    float ic = 1.0f / fmaxf((float)(s1 - s0), 1.0f);
    float4* dst = (float4*)(agg + (size_t)n * FIN + fbase);
    dst[0] = make_float4(a[0] * ic, a[1] * ic, a[2] * ic, a[3] * ic);
    dst[1] = make_float4(a[4] * ic, a[5] * ic, a[6] * ic, a[7] * ic);
}

// ---------------------------------------------------------------------------
// Path A, stage 2: streaming GEMM. Phase A' = coalesced float4 streams of
// agg + x into the swizzled LDS tile (no gather, no latency exposure).
// Phase B + epilogue identical to the fused kernel.
// ---------------------------------------------------------------------------
__global__ __launch_bounds__(1024, 8) void gemm_kernel(
    const float* __restrict__ agg, const float* __restrict__ x,
    const float* __restrict__ Wt, const float* __restrict__ b1,
    const float* __restrict__ W2l, const float* __restrict__ W2r,
    float* __restrict__ g, float* __restrict__ r)
{
    __shared__ float smem_f[256 * 64];   // 64 KB

    const int t  = threadIdx.x;
    const int nb = blockIdx.x * 64;
    const int l  = t & 63;

    {
        const int n_loc = t >> 4;
        const int ft    = t & 15;
        const int fbase = ft * 8;
        const int n     = nb + n_loc;
        const bool valid = (n < NN);
        const float4 z = make_float4(0.f, 0.f, 0.f, 0.f);
        const float4* ap = (const float4*)(agg + (size_t)(valid ? n : 0) * FIN + fbase);
        const float4* sp = (const float4*)(x   + (size_t)(valid ? n : 0) * FIN + fbase);
        float4 a0 = valid ? ap[0] : z, a1 = valid ? ap[1] : z;
        float4 s0 = valid ? sp[0] : z, s1 = valid ? sp[1] : z;
        float av[8] = {a0.x, a0.y, a0.z, a0.w, a1.x, a1.y, a1.z, a1.w};
        float sv[8] = {s0.x, s0.y, s0.z, s0.w, s1.x, s1.y, s1.z, s1.w};
#pragma unroll
        for (int k = 0; k < 8; ++k) {
            int f = fbase + k;
            smem_f[f * 64 + (n_loc ^ ((f >> 3) & 31))] = av[k];
        }
#pragma unroll
        for (int k = 0; k < 8; ++k) {
            int f = FIN + fbase + k;
            smem_f[f * 64 + (n_loc ^ ((f >> 3) & 31))] = sv[k];
        }
    }
    __syncthreads();

    const int w  = __builtin_amdgcn_readfirstlane(t >> 6);  // 0..15
    const int jb = w * 16;

    float o[16];
#pragma unroll
    for (int i = 0; i < 16; ++i) o[i] = 0.0f;

#pragma unroll 1
    for (int k2 = 0; k2 < 2 * FIN; ++k2) {
        float av = smem_f[k2 * 64 + (l ^ ((k2 >> 3) & 31))];
        const float* wrow = Wt + (size_t)k2 * HID + jb;   // wave-uniform
#pragma unroll
        for (int i = 0; i < 16; ++i) o[i] += av * wrow[i];
    }

    float sq = 0.f, g0 = 0.f, g1 = 0.f, r0 = 0.f, r1 = 0.f;
    const float* b1w  = b1  + jb;
    const float* w2la = W2l + jb;
    const float* w2lb = W2l + HID + jb;
    const float* w2ra = W2r + jb;
    const float* w2rb = W2r + HID + jb;
#pragma unroll
    for (int i = 0; i < 16; ++i) {
        float oo = o[i] + b1w[i];
        sq += oo * oo;
        float p = fmaxf(oo, 0.0f);           // relu(o/D) = relu(o)/D
        g0 += p * w2la[i];
        g1 += p * w2lb[i];
        r0 += p * w2ra[i];
        r1 += p * w2rb[i];
    }

    __syncthreads();
    smem_f[0 * 1024 + t] = sq;
    smem_f[1 * 1024 + t] = g0;
    smem_f[2 * 1024 + t] = g1;
    smem_f[3 * 1024 + t] = r0;
    smem_f[4 * 1024 + t] = r1;
    __syncthreads();

    if (t < 64) {
        int n2 = nb + t;
        float sqs = 0.f, G0 = 0.f, G1 = 0.f, R0 = 0.f, R1 = 0.f;
#pragma unroll
        for (int ww = 0; ww < 16; ++ww) {
            sqs += smem_f[0 * 1024 + ww * 64 + t];
            G0  += smem_f[1 * 1024 + ww * 64 + t];
            G1  += smem_f[2 * 1024 + ww * 64 + t];
            R0  += smem_f[3 * 1024 + ww * 64 + t];
            R1  += smem_f[4 * 1024 + ww * 64 + t];
        }
        float inv = 1.0f / fmaxf(sqrtf(sqs), FEPS);
        if (n2 < NN) {
            g[2 * (size_t)n2]     = G0 * inv;
            g[2 * (size_t)n2 + 1] = G1 * inv;
            r[2 * (size_t)n2]     = R0 * inv;
            r[2 * (size_t)n2 + 1] = R1 * inv;
        }
    }
}

// ---------------------------------------------------------------------------
// Paths B/C: fused layer-1 (R9 structure; B = fp16 gather, C = fp32).
// ---------------------------------------------------------------------------
template <bool HALFX>
__global__ __launch_bounds__(1024, 8) void layer1_kernel(
    const int* __restrict__ off, const int* __restrict__ col,
    const float* __restrict__ x, const __half* __restrict__ xh,
    const float* __restrict__ Wt, const float* __restrict__ b1,
    const float* __restrict__ W2l, const float* __restrict__ W2r,
    float* __restrict__ g, float* __restrict__ r)
{
    __shared__ float smem_f[256 * 64];

    const int t  = threadIdx.x;
    const int nb = blockIdx.x * 64;
    const int l  = t & 63;

    {
        const int n_loc = t >> 4;
        const int ft    = t & 15;
        const int fbase = ft * 8;
        const int n     = nb + n_loc;
        const bool valid = (n < NN);

        float a[8];
#pragma unroll
        for (int i = 0; i < 8; ++i) a[i] = 0.0f;

        int s0 = 0, s1 = 0;
        if (valid) { s0 = off[n]; s1 = off[n + 1]; }

        int i = s0;
        if (HALFX) {
            for (; i + 3 < s1; i += 4) {
                int c0 = clampN(col[i]);
                int c1 = clampN(col[i + 1]);
                int c2 = clampN(col[i + 2]);
                int c3 = clampN(col[i + 3]);
                uint4 v0 = *(const uint4*)(xh + (size_t)c0 * FIN + fbase);
                uint4 v1 = *(const uint4*)(xh + (size_t)c1 * FIN + fbase);
                uint4 v2 = *(const uint4*)(xh + (size_t)c2 * FIN + fbase);
                uint4 v3 = *(const uint4*)(xh + (size_t)c3 * FIN + fbase);
#pragma unroll
                for (int u = 0; u < 4; ++u) {
                    float2 f0 = __half22float2(__builtin_bit_cast(__half2, (&v0.x)[u]));
                    float2 f1 = __half22float2(__builtin_bit_cast(__half2, (&v1.x)[u]));
                    float2 f2 = __half22float2(__builtin_bit_cast(__half2, (&v2.x)[u]));
                    float2 f3 = __half22float2(__builtin_bit_cast(__half2, (&v3.x)[u]));
                    a[2 * u]     += (f0.x + f1.x) + (f2.x + f3.x);
                    a[2 * u + 1] += (f0.y + f1.y) + (f2.y + f3.y);
                }
            }
            for (; i < s1; ++i) {
                int c0 = clampN(col[i]);
                uint4 v0 = *(const uint4*)(xh + (size_t)c0 * FIN + fbase);
#pragma unroll
                for (int u = 0; u < 4; ++u) {
                    float2 f0 = __half22float2(__builtin_bit_cast(__half2, (&v0.x)[u]));
                    a[2 * u]     += f0.x;
                    a[2 * u + 1] += f0.y;
                }
            }
        } else {
            for (; i < s1; ++i) {
                int c0 = clampN(col[i]);
                const float4* p0 = (const float4*)(x + (size_t)c0 * FIN + fbase);
                float4 v00 = p0[0], v01 = p0[1];
                a[0] += v00.x; a[1] += v00.y; a[2] += v00.z; a[3] += v00.w;
                a[4] += v01.x; a[5] += v01.y; a[6] += v01.z; a[7] += v01.w;
            }
        }
        float ic = 1.0f / fmaxf((float)(s1 - s0), 1.0f);
#pragma unroll
        for (int k = 0; k < 8; ++k) {
            int f = fbase + k;
            smem_f[f * 64 + (n_loc ^ ((f >> 3) & 31))] = a[k] * ic;
        }
        const float4* sp = (const float4*)(x + (size_t)(valid ? n : 0) * FIN + fbase);
        float4 s0v = valid ? sp[0] : make_float4(0.f, 0.f, 0.f, 0.f);
        float4 s1v = valid ? sp[1] : make_float4(0.f, 0.f, 0.f, 0.f);
        float sv[8] = {s0v.x, s0v.y, s0v.z, s0v.w, s1v.x, s1v.y, s1v.z, s1v.w};
#pragma unroll
        for (int k = 0; k < 8; ++k) {
            int f = FIN + fbase + k;
            smem_f[f * 64 + (n_loc ^ ((f >> 3) & 31))] = sv[k];
        }
    }
    __syncthreads();

    const int w  = __builtin_amdgcn_readfirstlane(t >> 6);
    const int jb = w * 16;

    float o[16];
#pragma unroll
    for (int i = 0; i < 16; ++i) o[i] = 0.0f;

#pragma unroll 1
    for (int k2 = 0; k2 < 2 * FIN; ++k2) {
        float av = smem_f[k2 * 64 + (l ^ ((k2 >> 3) & 31))];
        const float* wrow = Wt + (size_t)k2 * HID + jb;
#pragma unroll
        for (int i = 0; i < 16; ++i) o[i] += av * wrow[i];
    }

    float sq = 0.f, g0 = 0.f, g1 = 0.f, r0 = 0.f, r1 = 0.f;
    const float* b1w  = b1  + jb;
    const float* w2la = W2l + jb;
    const float* w2lb = W2l + HID + jb;
    const float* w2ra = W2r + jb;
    const float* w2rb = W2r + HID + jb;
#pragma unroll
    for (int i = 0; i < 16; ++i) {
        float oo = o[i] + b1w[i];
        sq += oo * oo;
        float p = fmaxf(oo, 0.0f);
        g0 += p * w2la[i];
        g1 += p * w2lb[i];
        r0 += p * w2ra[i];
        r1 += p * w2rb[i];
    }

    __syncthreads();
    smem_f[0 * 1024 + t] = sq;
    smem_f[1 * 1024 + t] = g0;
    smem_f[2 * 1024 + t] = g1;
    smem_f[3 * 1024 + t] = r0;
    smem_f[4 * 1024 + t] = r1;
    __syncthreads();

    if (t < 64) {
        int n2 = nb + t;
        float sqs = 0.f, G0 = 0.f, G1 = 0.f, R0 = 0.f, R1 = 0.f;
#pragma unroll
        for (int ww = 0; ww < 16; ++ww) {
            sqs += smem_f[0 * 1024 + ww * 64 + t];
            G0  += smem_f[1 * 1024 + ww * 64 + t];
            G1  += smem_f[2 * 1024 + ww * 64 + t];
            R0  += smem_f[3 * 1024 + ww * 64 + t];
            R1  += smem_f[4 * 1024 + ww * 64 + t];
        }
        float inv = 1.0f / fmaxf(sqrtf(sqs), FEPS);
        if (n2 < NN) {
            g[2 * (size_t)n2]     = G0 * inv;
            g[2 * (size_t)n2 + 1] = G1 * inv;
            r[2 * (size_t)n2]     = R0 * inv;
            r[2 * (size_t)n2 + 1] = R1 * inv;
        }
    }
}

// layer-2 mean via CSR gather of g, +b2, +lin_r, L2-normalize, log_softmax
__global__ __launch_bounds__(256) void finalize_kernel(
    const int* __restrict__ off, const int* __restrict__ col,
    const float* __restrict__ g, const float* __restrict__ r,
    const float* __restrict__ b2,
    float* __restrict__ out)
{
    int n = blockIdx.x * 256 + threadIdx.x;
    if (n >= NN) return;
    int s0 = off[n], s1 = off[n + 1];
    float z0 = 0.0f, z1 = 0.0f, y0b = 0.0f, y1b = 0.0f;
    int i = s0;
    for (; i + 1 < s1; i += 2) {
        int sa = clampN(col[i]);
        int sb = clampN(col[i + 1]);
        float2 va = *(const float2*)(g + 2 * (size_t)sa);
        float2 vb = *(const float2*)(g + 2 * (size_t)sb);
        z0 += va.x; z1 += va.y;
        y0b += vb.x; y1b += vb.y;
    }
    if (i < s1) {
        int sa = clampN(col[i]);
        float2 va = *(const float2*)(g + 2 * (size_t)sa);
        z0 += va.x; z1 += va.y;
    }
    z0 += y0b; z1 += y1b;
    float ic = 1.0f / fmaxf((float)(s1 - s0), 1.0f);
    z0 = z0 * ic + b2[0] + r[2 * (size_t)n];
    z1 = z1 * ic + b2[1] + r[2 * (size_t)n + 1];
    float d = 1.0f / fmaxf(sqrtf(z0 * z0 + z1 * z1), FEPS);
    float y0 = z0 * d, y1 = z1 * d;
    float m = fmaxf(y0, y1);
    float l = m + logf(__expf(y0 - m) + __expf(y1 - m));
    out[2 * (size_t)n]     = y0 - l;
    out[2 * (size_t)n + 1] = y1 - l;
}

// ---------------------------------------------------------------------------
extern "C" void kernel_launch(void* const* d_in, const int* in_sizes, int n_in,
                              void* d_out, int out_size, void* d_ws, size_t ws_size,
                              hipStream_t stream) {
    // setup_inputs order: x, edge_index, W1_l, b1, W1_r, W2_l, b2, W2_r
    const float* x   = (const float*)d_in[0];
    const int*   ei  = (const int*)d_in[1];
    const float* W1l = (const float*)d_in[2];
    const float* b1  = (const float*)d_in[3];
    const float* W1r = (const float*)d_in[4];
    const float* W2l = (const float*)d_in[5];
    const float* b2  = (const float*)d_in[6];
    const float* W2r = (const float*)d_in[7];

    const int nsb = (NN + 1023) / 1024;          // 98 scan blocks
    const int ncv = (NN * FIN / 8 + 255) / 256;  // convert blocks
    const int ecb = (NE + 255) / 256;            // edge blocks

    const size_t tailWords = (size_t)2 * NN + (NN + 1) + NE + 4 * NN + 128;
    const size_t needB = (size_t)256 * 256 * 4 + (size_t)NN * FIN * 2 +
                         tailWords * 4;
    const size_t needA = needB + (size_t)NN * FIN * 4;   // + fp32 agg

    // host-side constants: graph-safe
    bool pathA = (ws_size >= needA);
    bool pathB = !pathA && (ws_size >= needB);
    bool half  = pathA || pathB;

    char* p = (char*)d_ws;
    float* Wt = (float*)p;                p += (size_t)256 * 256 * 4;
    __half* xh = nullptr;
    if (half) { xh = (__half*)p;          p += (size_t)NN * FIN * 2; }
    float* agg = nullptr;
    if (pathA) { agg = (float*)p;         p += (size_t)NN * FIN * 4; }

    int*   cnt  = (int*)p;
    int*   cur  = cnt + NN;
    int*   off  = cur + NN;                      // NN+1
    int*   col  = off + NN + 1;                  // NE
    float* g    = (float*)(col + NE);            // NN*2
    float* r    = g + 2 * (size_t)NN;            // NN*2
    int*   bsum = (int*)(r + 2 * (size_t)NN);    // 128

    hipMemsetAsync(cnt, 0, 2 * (size_t)NN * sizeof(int), stream);

    int cv = half ? ncv : 0;
    setup_kernel<<<256 + cv + ecb, 256, 0, stream>>>(ei, x, W1l, W1r, Wt, xh,
                                                     cnt, cv);
    scan_a_kernel<<<nsb, 1024, 0, stream>>>(cnt, off, bsum);
    scan_b_kernel<<<1, 128, 0, stream>>>(bsum, off, nsb);
    scan_c_kernel<<<nsb, 1024, 0, stream>>>(bsum, off);
    fill_kernel<<<ecb, 256, 0, stream>>>(ei, off, cur, col);

    if (pathA) {
        gather_kernel<<<(NN * 16 + 255) / 256, 256, 0, stream>>>(off, col, xh,
                                                                 agg);
        gemm_kernel<<<(NN + 63) / 64, 1024, 0, stream>>>(agg, x, Wt, b1,
                                                         W2l, W2r, g, r);
    } else if (pathB) {
        layer1_kernel<true><<<(NN + 63) / 64, 1024, 0, stream>>>(
            off, col, x, xh, Wt, b1, W2l, W2r, g, r);
    } else {
        layer1_kernel<false><<<(NN + 63) / 64, 1024, 0, stream>>>(
            off, col, x, xh, Wt, b1, W2l, W2r, g, r);
    }
    finalize_kernel<<<(NN + 255) / 256, 256, 0, stream>>>(off, col, g, r, b2,
                                                          (float*)d_out);
}

// Round 14
// 415.138 us; speedup vs baseline: 1.0757x; 1.0757x over previous
//
#include <hip/hip_runtime.h>
#include <hip/hip_fp16.h>

// Problem constants (from reference)
#define NN  100000   // nodes
#define FIN 128      // in features
#define HID 256      // hidden
#define NE  600000   // edges
#define FEPS 1e-12f

// ---------------------------------------------------------------------------
// Workspace layout:
//  Path A (~82.3 MB): Wt[256*256]f | xh[NN*FIN]h | agg[NN*FIN]f | cnt|cur|
//                     off|col | g|r | bsum
//  Path B (~31.1 MB): same minus agg (fused layer1). Path C: fp32 fused.
// Evidence log:
//  - R5: bf16 FEATURES fail precision (1/||z|| amplification); fp16 OK
//    (absmax 0.0156 vs thr 0.0327). ws_size >= 31.1 MB.
//  - R6/R7/R8: occupancy lever exhausted at 32 waves/CU (291 us fused).
//  - R9: bytes not the limit. R10: divergent __shfl broken. R11: LDS fp32
//    atomics 3x slow (CAS codegen). R12: wider batch neutral (spills).
//  - R13: SPLIT WINS: barrier-free gather ~<50 us (degree skew absorbed by
//    wave scheduling; ws_size >= 82.3 MB proven). gemm now the bottleneck:
//    265 us @ VALUBusy 45% — `unroll 1` k2 loop serializes ds_read+s_load
//    latency against 16 FMAs. R14: unroll k2 by 4 (batched loads, 64 FMAs).
// ---------------------------------------------------------------------------

__device__ __forceinline__ int clampN(int v) {
    return ((unsigned)v < (unsigned)NN) ? v : 0;
}
// int64 vs int32 edge_index: little-endian int64 (<2^31) => odd words all 0.
__device__ __forceinline__ int detect4(const int* ei) {
    return ((ei[1] | ei[3] | ei[5] | ei[7]) == 0) ? 1 : 0;
}
__device__ __forceinline__ int ld_src(const int* ei, int e, int f) {
    return f ? ei[2 * e] : ei[e];
}
__device__ __forceinline__ int ld_dst(const int* ei, int e, int f) {
    return f ? ei[2 * (NE + e)] : ei[NE + e];
}

// ---------------------------------------------------------------------------
// Setup (fused): blocks [0,256) weight transpose; [256,256+ncv) x->fp16;
// [256+ncv, ...) in-degree count (cnt pre-zeroed by memset).
// ---------------------------------------------------------------------------
__global__ __launch_bounds__(256) void setup_kernel(
    const int* __restrict__ ei,
    const float* __restrict__ x,
    const float* __restrict__ W1l, const float* __restrict__ W1r,
    float* __restrict__ Wt, __half* __restrict__ xh,
    int* __restrict__ cnt, int ncv)
{
    int b = blockIdx.x;
    int t = threadIdx.x;
    if (b < 256) {
        int k2 = b;
        float v = (k2 < FIN) ? W1l[(size_t)t * FIN + k2]
                             : W1r[(size_t)t * FIN + (k2 - FIN)];
        Wt[(size_t)k2 * HID + t] = v;
    } else if (b < 256 + ncv) {
        int idx = (b - 256) * 256 + t;           // 8-float group
        if (idx < NN * FIN / 8) {
            const float4* px = (const float4*)(x + (size_t)idx * 8);
            float4 v0 = px[0], v1 = px[1];
            __half2 h0 = __float22half2_rn(make_float2(v0.x, v0.y));
            __half2 h1 = __float22half2_rn(make_float2(v0.z, v0.w));
            __half2 h2 = __float22half2_rn(make_float2(v1.x, v1.y));
            __half2 h3 = __float22half2_rn(make_float2(v1.z, v1.w));
            uint4 u;
            u.x = __builtin_bit_cast(unsigned, h0);
            u.y = __builtin_bit_cast(unsigned, h1);
            u.z = __builtin_bit_cast(unsigned, h2);
            u.w = __builtin_bit_cast(unsigned, h3);
            ((uint4*)xh)[idx] = u;
        }
    } else {
        int e = (b - 256 - ncv) * 256 + t;
        if (e < NE) {
            int f = detect4(ei);
            atomicAdd(cnt + clampN(ld_dst(ei, e, f)), 1);
        }
    }
}

// 3-phase parallel exclusive scan of cnt[NN] -> off[NN+1]
__global__ __launch_bounds__(1024) void scan_a_kernel(
    const int* __restrict__ cnt, int* __restrict__ off, int* __restrict__ bsum)
{
    __shared__ int sm[1024];
    int t = threadIdx.x;
    int idx = blockIdx.x * 1024 + t;
    int v = (idx < NN) ? cnt[idx] : 0;
    sm[t] = v;
    __syncthreads();
    for (int d = 1; d < 1024; d <<= 1) {
        int w = (t >= d) ? sm[t - d] : 0;
        __syncthreads();
        sm[t] += w;
        __syncthreads();
    }
    if (idx < NN) off[idx] = sm[t] - v;
    if (t == 1023) bsum[blockIdx.x] = sm[1023];
}
__global__ __launch_bounds__(128) void scan_b_kernel(
    int* __restrict__ bsum, int* __restrict__ off, int nblocks)
{
    __shared__ int sm[128];
    int t = threadIdx.x;
    int v = (t < nblocks) ? bsum[t] : 0;
    sm[t] = v;
    __syncthreads();
    for (int d = 1; d < 128; d <<= 1) {
        int w = (t >= d) ? sm[t - d] : 0;
        __syncthreads();
        sm[t] += w;
        __syncthreads();
    }
    if (t < nblocks) bsum[t] = sm[t] - v;
    if (t == 0) off[NN] = NE;
}
__global__ __launch_bounds__(1024) void scan_c_kernel(
    const int* __restrict__ bsum, int* __restrict__ off)
{
    int idx = blockIdx.x * 1024 + threadIdx.x;
    if (idx < NN) off[idx] += bsum[blockIdx.x];
}

// place src ids into CSR slots
__global__ __launch_bounds__(256) void fill_kernel(
    const int* __restrict__ ei,
    const int* __restrict__ off, int* __restrict__ cur, int* __restrict__ col)
{
    int e = blockIdx.x * 256 + threadIdx.x;
    if (e >= NE) return;
    int f = detect4(ei);
    int src = clampN(ld_src(ei, e, f));
    int dst = clampN(ld_dst(ei, e, f));
    int p = atomicAdd(cur + dst, 1);
    col[off[dst] + p] = src;
}

// ---------------------------------------------------------------------------
// Path A, stage 1: barrier-free gather. 1 thread per (node, 16B fp16 chunk);
// 4-wide independent-load loop; mean written to global agg (fp32).
// No LDS, no __syncthreads: a high-degree straggler holds only its own wave.
// ---------------------------------------------------------------------------
__global__ __launch_bounds__(256) void gather_kernel(
    const int* __restrict__ off, const int* __restrict__ col,
    const __half* __restrict__ xh, float* __restrict__ agg)
{
    int idx = blockIdx.x * 256 + threadIdx.x;
    if (idx >= NN * 16) return;
    int n     = idx >> 4;
    int ft    = idx & 15;
    int fbase = ft * 8;

    float a[8];
#pragma unroll
    for (int i = 0; i < 8; ++i) a[i] = 0.0f;

    int s0 = off[n], s1 = off[n + 1];
    int i = s0;
    for (; i + 3 < s1; i += 4) {            // 4 independent 16B loads
        int c0 = clampN(col[i]);
        int c1 = clampN(col[i + 1]);
        int c2 = clampN(col[i + 2]);
        int c3 = clampN(col[i + 3]);
        uint4 v0 = *(const uint4*)(xh + (size_t)c0 * FIN + fbase);
        uint4 v1 = *(const uint4*)(xh + (size_t)c1 * FIN + fbase);
        uint4 v2 = *(const uint4*)(xh + (size_t)c2 * FIN + fbase);
        uint4 v3 = *(const uint4*)(xh + (size_t)c3 * FIN + fbase);
#pragma unroll
        for (int u = 0; u < 4; ++u) {
            float2 f0 = __half22float2(__builtin_bit_cast(__half2, (&v0.x)[u]));
            float2 f1 = __half22float2(__builtin_bit_cast(__half2, (&v1.x)[u]));
            float2 f2 = __half22float2(__builtin_bit_cast(__half2, (&v2.x)[u]));
            float2 f3 = __half22float2(__builtin_bit_cast(__half2, (&v3.x)[u]));
            a[2 * u]     += (f0.x + f1.x) + (f2.x + f3.x);
            a[2 * u + 1] += (f0.y + f1.y) + (f2.y + f3.y);
        }
    }
    for (; i < s1; ++i) {
        int c0 = clampN(col[i]);
        uint4 v0 = *(const uint4*)(xh + (size_t)c0 * FIN + fbase);
#pragma unroll
        for (int u = 0; u < 4; ++u) {
            float2 f0 = __half22float2(__builtin_bit_cast(__half2, (&v0.x)[u]));
            a[2 * u]     += f0.x;
            a[2 * u + 1] += f0.y;
        }
    }
    float ic = 1.0f / fmaxf((float)(s1 - s0), 1.0f);
    float4* dst = (float4*)(agg + (size_t)n * FIN + fbase);
    dst[0] = make_float4(a[0] * ic, a[1] * ic, a[2] * ic, a[3] * ic);
    dst[1] = make_float4(a[4] * ic, a[5] * ic, a[6] * ic, a[7] * ic);
}

// ---------------------------------------------------------------------------
// Shared phase-B + epilogue body (R14: k2 loop unrolled x4 — batched
// 4 ds_reads + 4 weight rows, then 64 FMAs; hides lgkmcnt latency).
// ---------------------------------------------------------------------------
__device__ __forceinline__ void phaseB_epilogue(
    float* smem_f, int t, int l, int nb,
    const float* __restrict__ Wt, const float* __restrict__ b1,
    const float* __restrict__ W2l, const float* __restrict__ W2r,
    float* __restrict__ g, float* __restrict__ r)
{
    const int w  = __builtin_amdgcn_readfirstlane(t >> 6);  // 0..15
    const int jb = w * 16;

    float o[16];
#pragma unroll
    for (int i = 0; i < 16; ++i) o[i] = 0.0f;

#pragma unroll 1
    for (int k2 = 0; k2 < 2 * FIN; k2 += 4) {
        // swizzle column is quad-invariant: (k2..k2+3)>>3 identical
        const int nc = l ^ ((k2 >> 3) & 31);
        float av0 = smem_f[(k2 + 0) * 64 + nc];
        float av1 = smem_f[(k2 + 1) * 64 + nc];
        float av2 = smem_f[(k2 + 2) * 64 + nc];
        float av3 = smem_f[(k2 + 3) * 64 + nc];
        const float* w0 = Wt + (size_t)(k2 + 0) * HID + jb;  // wave-uniform
        const float* w1 = Wt + (size_t)(k2 + 1) * HID + jb;
        const float* w2 = Wt + (size_t)(k2 + 2) * HID + jb;
        const float* w3 = Wt + (size_t)(k2 + 3) * HID + jb;
#pragma unroll
        for (int i = 0; i < 16; ++i)
            o[i] += (av0 * w0[i] + av1 * w1[i]) + (av2 * w2[i] + av3 * w3[i]);
    }

    float sq = 0.f, g0 = 0.f, g1 = 0.f, r0 = 0.f, r1 = 0.f;
    const float* b1w  = b1  + jb;
    const float* w2la = W2l + jb;
    const float* w2lb = W2l + HID + jb;
    const float* w2ra = W2r + jb;
    const float* w2rb = W2r + HID + jb;
#pragma unroll
    for (int i = 0; i < 16; ++i) {
        float oo = o[i] + b1w[i];
        sq += oo * oo;
        float p = fmaxf(oo, 0.0f);           // relu(o/D) = relu(o)/D
        g0 += p * w2la[i];
        g1 += p * w2lb[i];
        r0 += p * w2ra[i];
        r1 += p * w2rb[i];
    }

    __syncthreads();                          // tile dead; reuse as overlay
    smem_f[0 * 1024 + t] = sq;
    smem_f[1 * 1024 + t] = g0;
    smem_f[2 * 1024 + t] = g1;
    smem_f[3 * 1024 + t] = r0;
    smem_f[4 * 1024 + t] = r1;
    __syncthreads();

    if (t < 64) {
        int n2 = nb + t;
        float sqs = 0.f, G0 = 0.f, G1 = 0.f, R0 = 0.f, R1 = 0.f;
#pragma unroll
        for (int ww = 0; ww < 16; ++ww) {
            sqs += smem_f[0 * 1024 + ww * 64 + t];
            G0  += smem_f[1 * 1024 + ww * 64 + t];
            G1  += smem_f[2 * 1024 + ww * 64 + t];
            R0  += smem_f[3 * 1024 + ww * 64 + t];
            R1  += smem_f[4 * 1024 + ww * 64 + t];
        }
        float inv = 1.0f / fmaxf(sqrtf(sqs), FEPS);
        if (n2 < NN) {
            g[2 * (size_t)n2]     = G0 * inv;
            g[2 * (size_t)n2 + 1] = G1 * inv;
            r[2 * (size_t)n2]     = R0 * inv;
            r[2 * (size_t)n2 + 1] = R1 * inv;
        }
    }
}

// ---------------------------------------------------------------------------
// Path A, stage 2: streaming GEMM. Phase A' = coalesced float4 streams of
// agg + x into the swizzled LDS tile.
// ---------------------------------------------------------------------------
__global__ __launch_bounds__(1024, 8) void gemm_kernel(
    const float* __restrict__ agg, const float* __restrict__ x,
    const float* __restrict__ Wt, const float* __restrict__ b1,
    const float* __restrict__ W2l, const float* __restrict__ W2r,
    float* __restrict__ g, float* __restrict__ r)
{
    __shared__ float smem_f[256 * 64];   // 64 KB

    const int t  = threadIdx.x;
    const int nb = blockIdx.x * 64;
    const int l  = t & 63;

    {
        const int n_loc = t >> 4;
        const int ft    = t & 15;
        const int fbase = ft * 8;
        const int n     = nb + n_loc;
        const bool valid = (n < NN);
        const float4 z = make_float4(0.f, 0.f, 0.f, 0.f);
        const float4* ap = (const float4*)(agg + (size_t)(valid ? n : 0) * FIN + fbase);
        const float4* sp = (const float4*)(x   + (size_t)(valid ? n : 0) * FIN + fbase);
        float4 a0 = valid ? ap[0] : z, a1 = valid ? ap[1] : z;
        float4 s0 = valid ? sp[0] : z, s1 = valid ? sp[1] : z;
        float av[8] = {a0.x, a0.y, a0.z, a0.w, a1.x, a1.y, a1.z, a1.w};
        float sv[8] = {s0.x, s0.y, s0.z, s0.w, s1.x, s1.y, s1.z, s1.w};
#pragma unroll
        for (int k = 0; k < 8; ++k) {
            int f = fbase + k;
            smem_f[f * 64 + (n_loc ^ ((f >> 3) & 31))] = av[k];
        }
#pragma unroll
        for (int k = 0; k < 8; ++k) {
            int f = FIN + fbase + k;
            smem_f[f * 64 + (n_loc ^ ((f >> 3) & 31))] = sv[k];
        }
    }
    __syncthreads();

    phaseB_epilogue(smem_f, t, l, nb, Wt, b1, W2l, W2r, g, r);
}

// ---------------------------------------------------------------------------
// Paths B/C: fused layer-1 (B = fp16 gather, C = fp32).
// ---------------------------------------------------------------------------
template <bool HALFX>
__global__ __launch_bounds__(1024, 8) void layer1_kernel(
    const int* __restrict__ off, const int* __restrict__ col,
    const float* __restrict__ x, const __half* __restrict__ xh,
    const float* __restrict__ Wt, const float* __restrict__ b1,
    const float* __restrict__ W2l, const float* __restrict__ W2r,
    float* __restrict__ g, float* __restrict__ r)
{
    __shared__ float smem_f[256 * 64];

    const int t  = threadIdx.x;
    const int nb = blockIdx.x * 64;
    const int l  = t & 63;

    {
        const int n_loc = t >> 4;
        const int ft    = t & 15;
        const int fbase = ft * 8;
        const int n     = nb + n_loc;
        const bool valid = (n < NN);

        float a[8];
#pragma unroll
        for (int i = 0; i < 8; ++i) a[i] = 0.0f;

        int s0 = 0, s1 = 0;
        if (valid) { s0 = off[n]; s1 = off[n + 1]; }

        int i = s0;
        if (HALFX) {
            for (; i + 3 < s1; i += 4) {
                int c0 = clampN(col[i]);
                int c1 = clampN(col[i + 1]);
                int c2 = clampN(col[i + 2]);
                int c3 = clampN(col[i + 3]);
                uint4 v0 = *(const uint4*)(xh + (size_t)c0 * FIN + fbase);
                uint4 v1 = *(const uint4*)(xh + (size_t)c1 * FIN + fbase);
                uint4 v2 = *(const uint4*)(xh + (size_t)c2 * FIN + fbase);
                uint4 v3 = *(const uint4*)(xh + (size_t)c3 * FIN + fbase);
#pragma unroll
                for (int u = 0; u < 4; ++u) {
                    float2 f0 = __half22float2(__builtin_bit_cast(__half2, (&v0.x)[u]));
                    float2 f1 = __half22float2(__builtin_bit_cast(__half2, (&v1.x)[u]));
                    float2 f2 = __half22float2(__builtin_bit_cast(__half2, (&v2.x)[u]));
                    float2 f3 = __half22float2(__builtin_bit_cast(__half2, (&v3.x)[u]));
                    a[2 * u]     += (f0.x + f1.x) + (f2.x + f3.x);
                    a[2 * u + 1] += (f0.y + f1.y) + (f2.y + f3.y);
                }
            }
            for (; i < s1; ++i) {
                int c0 = clampN(col[i]);
                uint4 v0 = *(const uint4*)(xh + (size_t)c0 * FIN + fbase);
#pragma unroll
                for (int u = 0; u < 4; ++u) {
                    float2 f0 = __half22float2(__builtin_bit_cast(__half2, (&v0.x)[u]));
                    a[2 * u]     += f0.x;
                    a[2 * u + 1] += f0.y;
                }
            }
        } else {
            for (; i < s1; ++i) {
                int c0 = clampN(col[i]);
                const float4* p0 = (const float4*)(x + (size_t)c0 * FIN + fbase);
                float4 v00 = p0[0], v01 = p0[1];
                a[0] += v00.x; a[1] += v00.y; a[2] += v00.z; a[3] += v00.w;
                a[4] += v01.x; a[5] += v01.y; a[6] += v01.z; a[7] += v01.w;
            }
        }
        float ic = 1.0f / fmaxf((float)(s1 - s0), 1.0f);
#pragma unroll
        for (int k = 0; k < 8; ++k) {
            int f = fbase + k;
            smem_f[f * 64 + (n_loc ^ ((f >> 3) & 31))] = a[k] * ic;
        }
        const float4* sp = (const float4*)(x + (size_t)(valid ? n : 0) * FIN + fbase);
        float4 s0v = valid ? sp[0] : make_float4(0.f, 0.f, 0.f, 0.f);
        float4 s1v = valid ? sp[1] : make_float4(0.f, 0.f, 0.f, 0.f);
        float sv[8] = {s0v.x, s0v.y, s0v.z, s0v.w, s1v.x, s1v.y, s1v.z, s1v.w};
#pragma unroll
        for (int k = 0; k < 8; ++k) {
            int f = FIN + fbase + k;
            smem_f[f * 64 + (n_loc ^ ((f >> 3) & 31))] = sv[k];
        }
    }
    __syncthreads();

    phaseB_epilogue(smem_f, t, l, nb, Wt, b1, W2l, W2r, g, r);
}

// layer-2 mean via CSR gather of g, +b2, +lin_r, L2-normalize, log_softmax
__global__ __launch_bounds__(256) void finalize_kernel(
    const int* __restrict__ off, const int* __restrict__ col,
    const float* __restrict__ g, const float* __restrict__ r,
    const float* __restrict__ b2,
    float* __restrict__ out)
{
    int n = blockIdx.x * 256 + threadIdx.x;
    if (n >= NN) return;
    int s0 = off[n], s1 = off[n + 1];
    float z0 = 0.0f, z1 = 0.0f, y0b = 0.0f, y1b = 0.0f;
    int i = s0;
    for (; i + 1 < s1; i += 2) {
        int sa = clampN(col[i]);
        int sb = clampN(col[i + 1]);
        float2 va = *(const float2*)(g + 2 * (size_t)sa);
        float2 vb = *(const float2*)(g + 2 * (size_t)sb);
        z0 += va.x; z1 += va.y;
        y0b += vb.x; y1b += vb.y;
    }
    if (i < s1) {
        int sa = clampN(col[i]);
        float2 va = *(const float2*)(g + 2 * (size_t)sa);
        z0 += va.x; z1 += va.y;
    }
    z0 += y0b; z1 += y1b;
    float ic = 1.0f / fmaxf((float)(s1 - s0), 1.0f);
    z0 = z0 * ic + b2[0] + r[2 * (size_t)n];
    z1 = z1 * ic + b2[1] + r[2 * (size_t)n + 1];
    float d = 1.0f / fmaxf(sqrtf(z0 * z0 + z1 * z1), FEPS);
    float y0 = z0 * d, y1 = z1 * d;
    float m = fmaxf(y0, y1);
    float l = m + logf(__expf(y0 - m) + __expf(y1 - m));
    out[2 * (size_t)n]     = y0 - l;
    out[2 * (size_t)n + 1] = y1 - l;
}

// ---------------------------------------------------------------------------
extern "C" void kernel_launch(void* const* d_in, const int* in_sizes, int n_in,
                              void* d_out, int out_size, void* d_ws, size_t ws_size,
                              hipStream_t stream) {
    // setup_inputs order: x, edge_index, W1_l, b1, W1_r, W2_l, b2, W2_r
    const float* x   = (const float*)d_in[0];
    const int*   ei  = (const int*)d_in[1];
    const float* W1l = (const float*)d_in[2];
    const float* b1  = (const float*)d_in[3];
    const float* W1r = (const float*)d_in[4];
    const float* W2l = (const float*)d_in[5];
    const float* b2  = (const float*)d_in[6];
    const float* W2r = (const float*)d_in[7];

    const int nsb = (NN + 1023) / 1024;          // 98 scan blocks
    const int ncv = (NN * FIN / 8 + 255) / 256;  // convert blocks
    const int ecb = (NE + 255) / 256;            // edge blocks

    const size_t tailWords = (size_t)2 * NN + (NN + 1) + NE + 4 * NN + 128;
    const size_t needB = (size_t)256 * 256 * 4 + (size_t)NN * FIN * 2 +
                         tailWords * 4;
    const size_t needA = needB + (size_t)NN * FIN * 4;   // + fp32 agg

    // host-side constants: graph-safe
    bool pathA = (ws_size >= needA);
    bool pathB = !pathA && (ws_size >= needB);
    bool half  = pathA || pathB;

    char* p = (char*)d_ws;
    float* Wt = (float*)p;                p += (size_t)256 * 256 * 4;
    __half* xh = nullptr;
    if (half) { xh = (__half*)p;          p += (size_t)NN * FIN * 2; }
    float* agg = nullptr;
    if (pathA) { agg = (float*)p;         p += (size_t)NN * FIN * 4; }

    int*   cnt  = (int*)p;
    int*   cur  = cnt + NN;
    int*   off  = cur + NN;                      // NN+1
    int*   col  = off + NN + 1;                  // NE
    float* g    = (float*)(col + NE);            // NN*2
    float* r    = g + 2 * (size_t)NN;            // NN*2
    int*   bsum = (int*)(r + 2 * (size_t)NN);    // 128

    hipMemsetAsync(cnt, 0, 2 * (size_t)NN * sizeof(int), stream);

    int cv = half ? ncv : 0;
    setup_kernel<<<256 + cv + ecb, 256, 0, stream>>>(ei, x, W1l, W1r, Wt, xh,
                                                     cnt, cv);
    scan_a_kernel<<<nsb, 1024, 0, stream>>>(cnt, off, bsum);
    scan_b_kernel<<<1, 128, 0, stream>>>(bsum, off, nsb);
    scan_c_kernel<<<nsb, 1024, 0, stream>>>(bsum, off);
    fill_kernel<<<ecb, 256, 0, stream>>>(ei, off, cur, col);

    if (pathA) {
        gather_kernel<<<(NN * 16 + 255) / 256, 256, 0, stream>>>(off, col, xh,
                                                                 agg);
        gemm_kernel<<<(NN + 63) / 64, 1024, 0, stream>>>(agg, x, Wt, b1,
                                                         W2l, W2r, g, r);
    } else if (pathB) {
        layer1_kernel<true><<<(NN + 63) / 64, 1024, 0, stream>>>(
            off, col, x, xh, Wt, b1, W2l, W2r, g, r);
    } else {
        layer1_kernel<false><<<(NN + 63) / 64, 1024, 0, stream>>>(
            off, col, x, xh, Wt, b1, W2l, W2r, g, r);
    }
    finalize_kernel<<<(NN + 255) / 256, 256, 0, stream>>>(off, col, g, r, b2,
                                                          (float*)d_out);
}

// Round 15
// 381.498 us; speedup vs baseline: 1.1705x; 1.0882x over previous
//
#include <hip/hip_runtime.h>
#include <hip/hip_fp16.h>

// Problem constants (from reference)
#define NN  100000   // nodes
#define FIN 128      // in features
#define HID 256      // hidden
#define NE  600000   // edges
#define FEPS 1e-12f

// ---------------------------------------------------------------------------
// Workspace layout:
//  Path A (~82.3 MB): Wt[256*256]f | xh[NN*FIN]h | agg[NN*FIN]f | cnt|cur|
//                     off|col | g|r | bsum
//  Path B (~31.1 MB): same minus agg (fused layer1). Path C: fp32 fused.
// Evidence log:
//  - R5: bf16 FEATURES fail precision (1/||z|| amplification); fp16 OK
//    (absmax 0.0156 vs thr 0.0327). ws_size >= 31.1 MB.
//  - R6/R7/R8: occupancy lever exhausted at 32 waves/CU (291 us fused).
//  - R9: bytes not the limit. R10: divergent __shfl broken. R11: LDS fp32
//    atomics 3x slow (CAS codegen). R12: wider batch neutral (spills).
//  - R13: SPLIT WINS: barrier-free gather <50 us (degree skew absorbed by
//    wave scheduling; ws_size >= 82.3 MB proven). gemm exposed: 265 us.
//  - R14: k2 unroll x4: VALUBusy 45->74%, 265->245 us. VALU-issue 181 us vs
//    83 us FMA floor => grouped-sum expression costs 6 VALU / 4 MACs.
//    R15: sequential fmaf chains -> exactly 4 v_fmac / 4 MACs.
// ---------------------------------------------------------------------------

__device__ __forceinline__ int clampN(int v) {
    return ((unsigned)v < (unsigned)NN) ? v : 0;
}
// int64 vs int32 edge_index: little-endian int64 (<2^31) => odd words all 0.
__device__ __forceinline__ int detect4(const int* ei) {
    return ((ei[1] | ei[3] | ei[5] | ei[7]) == 0) ? 1 : 0;
}
__device__ __forceinline__ int ld_src(const int* ei, int e, int f) {
    return f ? ei[2 * e] : ei[e];
}
__device__ __forceinline__ int ld_dst(const int* ei, int e, int f) {
    return f ? ei[2 * (NE + e)] : ei[NE + e];
}

// ---------------------------------------------------------------------------
// Setup (fused): blocks [0,256) weight transpose; [256,256+ncv) x->fp16;
// [256+ncv, ...) in-degree count (cnt pre-zeroed by memset).
// ---------------------------------------------------------------------------
__global__ __launch_bounds__(256) void setup_kernel(
    const int* __restrict__ ei,
    const float* __restrict__ x,
    const float* __restrict__ W1l, const float* __restrict__ W1r,
    float* __restrict__ Wt, __half* __restrict__ xh,
    int* __restrict__ cnt, int ncv)
{
    int b = blockIdx.x;
    int t = threadIdx.x;
    if (b < 256) {
        int k2 = b;
        float v = (k2 < FIN) ? W1l[(size_t)t * FIN + k2]
                             : W1r[(size_t)t * FIN + (k2 - FIN)];
        Wt[(size_t)k2 * HID + t] = v;
    } else if (b < 256 + ncv) {
        int idx = (b - 256) * 256 + t;           // 8-float group
        if (idx < NN * FIN / 8) {
            const float4* px = (const float4*)(x + (size_t)idx * 8);
            float4 v0 = px[0], v1 = px[1];
            __half2 h0 = __float22half2_rn(make_float2(v0.x, v0.y));
            __half2 h1 = __float22half2_rn(make_float2(v0.z, v0.w));
            __half2 h2 = __float22half2_rn(make_float2(v1.x, v1.y));
            __half2 h3 = __float22half2_rn(make_float2(v1.z, v1.w));
            uint4 u;
            u.x = __builtin_bit_cast(unsigned, h0);
            u.y = __builtin_bit_cast(unsigned, h1);
            u.z = __builtin_bit_cast(unsigned, h2);
            u.w = __builtin_bit_cast(unsigned, h3);
            ((uint4*)xh)[idx] = u;
        }
    } else {
        int e = (b - 256 - ncv) * 256 + t;
        if (e < NE) {
            int f = detect4(ei);
            atomicAdd(cnt + clampN(ld_dst(ei, e, f)), 1);
        }
    }
}

// 3-phase parallel exclusive scan of cnt[NN] -> off[NN+1]
__global__ __launch_bounds__(1024) void scan_a_kernel(
    const int* __restrict__ cnt, int* __restrict__ off, int* __restrict__ bsum)
{
    __shared__ int sm[1024];
    int t = threadIdx.x;
    int idx = blockIdx.x * 1024 + t;
    int v = (idx < NN) ? cnt[idx] : 0;
    sm[t] = v;
    __syncthreads();
    for (int d = 1; d < 1024; d <<= 1) {
        int w = (t >= d) ? sm[t - d] : 0;
        __syncthreads();
        sm[t] += w;
        __syncthreads();
    }
    if (idx < NN) off[idx] = sm[t] - v;
    if (t == 1023) bsum[blockIdx.x] = sm[1023];
}
__global__ __launch_bounds__(128) void scan_b_kernel(
    int* __restrict__ bsum, int* __restrict__ off, int nblocks)
{
    __shared__ int sm[128];
    int t = threadIdx.x;
    int v = (t < nblocks) ? bsum[t] : 0;
    sm[t] = v;
    __syncthreads();
    for (int d = 1; d < 128; d <<= 1) {
        int w = (t >= d) ? sm[t - d] : 0;
        __syncthreads();
        sm[t] += w;
        __syncthreads();
    }
    if (t < nblocks) bsum[t] = sm[t] - v;
    if (t == 0) off[NN] = NE;
}
__global__ __launch_bounds__(1024) void scan_c_kernel(
    const int* __restrict__ bsum, int* __restrict__ off)
{
    int idx = blockIdx.x * 1024 + threadIdx.x;
    if (idx < NN) off[idx] += bsum[blockIdx.x];
}

// place src ids into CSR slots
__global__ __launch_bounds__(256) void fill_kernel(
    const int* __restrict__ ei,
    const int* __restrict__ off, int* __restrict__ cur, int* __restrict__ col)
{
    int e = blockIdx.x * 256 + threadIdx.x;
    if (e >= NE) return;
    int f = detect4(ei);
    int src = clampN(ld_src(ei, e, f));
    int dst = clampN(ld_dst(ei, e, f));
    int p = atomicAdd(cur + dst, 1);
    col[off[dst] + p] = src;
}

// ---------------------------------------------------------------------------
// Path A, stage 1: barrier-free gather. 1 thread per (node, 16B fp16 chunk);
// 4-wide independent-load loop; mean written to global agg (fp32).
// ---------------------------------------------------------------------------
__global__ __launch_bounds__(256) void gather_kernel(
    const int* __restrict__ off, const int* __restrict__ col,
    const __half* __restrict__ xh, float* __restrict__ agg)
{
    int idx = blockIdx.x * 256 + threadIdx.x;
    if (idx >= NN * 16) return;
    int n     = idx >> 4;
    int ft    = idx & 15;
    int fbase = ft * 8;

    float a[8];
#pragma unroll
    for (int i = 0; i < 8; ++i) a[i] = 0.0f;

    int s0 = off[n], s1 = off[n + 1];
    int i = s0;
    for (; i + 3 < s1; i += 4) {            // 4 independent 16B loads
        int c0 = clampN(col[i]);
        int c1 = clampN(col[i + 1]);
        int c2 = clampN(col[i + 2]);
        int c3 = clampN(col[i + 3]);
        uint4 v0 = *(const uint4*)(xh + (size_t)c0 * FIN + fbase);
        uint4 v1 = *(const uint4*)(xh + (size_t)c1 * FIN + fbase);
        uint4 v2 = *(const uint4*)(xh + (size_t)c2 * FIN + fbase);
        uint4 v3 = *(const uint4*)(xh + (size_t)c3 * FIN + fbase);
#pragma unroll
        for (int u = 0; u < 4; ++u) {
            float2 f0 = __half22float2(__builtin_bit_cast(__half2, (&v0.x)[u]));
            float2 f1 = __half22float2(__builtin_bit_cast(__half2, (&v1.x)[u]));
            float2 f2 = __half22float2(__builtin_bit_cast(__half2, (&v2.x)[u]));
            float2 f3 = __half22float2(__builtin_bit_cast(__half2, (&v3.x)[u]));
            a[2 * u]     += (f0.x + f1.x) + (f2.x + f3.x);
            a[2 * u + 1] += (f0.y + f1.y) + (f2.y + f3.y);
        }
    }
    for (; i < s1; ++i) {
        int c0 = clampN(col[i]);
        uint4 v0 = *(const uint4*)(xh + (size_t)c0 * FIN + fbase);
#pragma unroll
        for (int u = 0; u < 4; ++u) {
            float2 f0 = __half22float2(__builtin_bit_cast(__half2, (&v0.x)[u]));
            a[2 * u]     += f0.x;
            a[2 * u + 1] += f0.y;
        }
    }
    float ic = 1.0f / fmaxf((float)(s1 - s0), 1.0f);
    float4* dst = (float4*)(agg + (size_t)n * FIN + fbase);
    dst[0] = make_float4(a[0] * ic, a[1] * ic, a[2] * ic, a[3] * ic);
    dst[1] = make_float4(a[4] * ic, a[5] * ic, a[6] * ic, a[7] * ic);
}

// ---------------------------------------------------------------------------
// Shared phase-B + epilogue body. R15: sequential fmaf chains into o[i]
// (exactly one v_fmac_f32 per MAC; weight element is the SGPR src).
// ---------------------------------------------------------------------------
__device__ __forceinline__ void phaseB_epilogue(
    float* smem_f, int t, int l, int nb,
    const float* __restrict__ Wt, const float* __restrict__ b1,
    const float* __restrict__ W2l, const float* __restrict__ W2r,
    float* __restrict__ g, float* __restrict__ r)
{
    const int w  = __builtin_amdgcn_readfirstlane(t >> 6);  // 0..15
    const int jb = w * 16;

    float o[16];
#pragma unroll
    for (int i = 0; i < 16; ++i) o[i] = 0.0f;

#pragma unroll 1
    for (int k2 = 0; k2 < 2 * FIN; k2 += 4) {
        // swizzle column is quad-invariant: (k2..k2+3)>>3 identical
        const int nc = l ^ ((k2 >> 3) & 31);
        float av0 = smem_f[(k2 + 0) * 64 + nc];
        float av1 = smem_f[(k2 + 1) * 64 + nc];
        float av2 = smem_f[(k2 + 2) * 64 + nc];
        float av3 = smem_f[(k2 + 3) * 64 + nc];
        const float* w0 = Wt + (size_t)(k2 + 0) * HID + jb;  // wave-uniform
        const float* w1 = Wt + (size_t)(k2 + 1) * HID + jb;
        const float* w2 = Wt + (size_t)(k2 + 2) * HID + jb;
        const float* w3 = Wt + (size_t)(k2 + 3) * HID + jb;
#pragma unroll
        for (int i = 0; i < 16; ++i) {
            float oi = o[i];
            oi = fmaf(av0, w0[i], oi);
            oi = fmaf(av1, w1[i], oi);
            oi = fmaf(av2, w2[i], oi);
            oi = fmaf(av3, w3[i], oi);
            o[i] = oi;
        }
    }

    float sq = 0.f, g0 = 0.f, g1 = 0.f, r0 = 0.f, r1 = 0.f;
    const float* b1w  = b1  + jb;
    const float* w2la = W2l + jb;
    const float* w2lb = W2l + HID + jb;
    const float* w2ra = W2r + jb;
    const float* w2rb = W2r + HID + jb;
#pragma unroll
    for (int i = 0; i < 16; ++i) {
        float oo = o[i] + b1w[i];
        sq = fmaf(oo, oo, sq);
        float p = fmaxf(oo, 0.0f);           // relu(o/D) = relu(o)/D
        g0 = fmaf(p, w2la[i], g0);
        g1 = fmaf(p, w2lb[i], g1);
        r0 = fmaf(p, w2ra[i], r0);
        r1 = fmaf(p, w2rb[i], r1);
    }

    __syncthreads();                          // tile dead; reuse as overlay
    smem_f[0 * 1024 + t] = sq;
    smem_f[1 * 1024 + t] = g0;
    smem_f[2 * 1024 + t] = g1;
    smem_f[3 * 1024 + t] = r0;
    smem_f[4 * 1024 + t] = r1;
    __syncthreads();

    if (t < 64) {
        int n2 = nb + t;
        float sqs = 0.f, G0 = 0.f, G1 = 0.f, R0 = 0.f, R1 = 0.f;
#pragma unroll
        for (int ww = 0; ww < 16; ++ww) {
            sqs += smem_f[0 * 1024 + ww * 64 + t];
            G0  += smem_f[1 * 1024 + ww * 64 + t];
            G1  += smem_f[2 * 1024 + ww * 64 + t];
            R0  += smem_f[3 * 1024 + ww * 64 + t];
            R1  += smem_f[4 * 1024 + ww * 64 + t];
        }
        float inv = 1.0f / fmaxf(sqrtf(sqs), FEPS);
        if (n2 < NN) {
            g[2 * (size_t)n2]     = G0 * inv;
            g[2 * (size_t)n2 + 1] = G1 * inv;
            r[2 * (size_t)n2]     = R0 * inv;
            r[2 * (size_t)n2 + 1] = R1 * inv;
        }
    }
}

// ---------------------------------------------------------------------------
// Path A, stage 2: streaming GEMM. Phase A' = coalesced float4 streams of
// agg + x into the swizzled LDS tile.
// ---------------------------------------------------------------------------
__global__ __launch_bounds__(1024, 8) void gemm_kernel(
    const float* __restrict__ agg, const float* __restrict__ x,
    const float* __restrict__ Wt, const float* __restrict__ b1,
    const float* __restrict__ W2l, const float* __restrict__ W2r,
    float* __restrict__ g, float* __restrict__ r)
{
    __shared__ float smem_f[256 * 64];   // 64 KB

    const int t  = threadIdx.x;
    const int nb = blockIdx.x * 64;
    const int l  = t & 63;

    {
        const int n_loc = t >> 4;
        const int ft    = t & 15;
        const int fbase = ft * 8;
        const int n     = nb + n_loc;
        const bool valid = (n < NN);
        const float4 z = make_float4(0.f, 0.f, 0.f, 0.f);
        const float4* ap = (const float4*)(agg + (size_t)(valid ? n : 0) * FIN + fbase);
        const float4* sp = (const float4*)(x   + (size_t)(valid ? n : 0) * FIN + fbase);
        float4 a0 = valid ? ap[0] : z, a1 = valid ? ap[1] : z;
        float4 s0 = valid ? sp[0] : z, s1 = valid ? sp[1] : z;
        float av[8] = {a0.x, a0.y, a0.z, a0.w, a1.x, a1.y, a1.z, a1.w};
        float sv[8] = {s0.x, s0.y, s0.z, s0.w, s1.x, s1.y, s1.z, s1.w};
#pragma unroll
        for (int k = 0; k < 8; ++k) {
            int f = fbase + k;
            smem_f[f * 64 + (n_loc ^ ((f >> 3) & 31))] = av[k];
        }
#pragma unroll
        for (int k = 0; k < 8; ++k) {
            int f = FIN + fbase + k;
            smem_f[f * 64 + (n_loc ^ ((f >> 3) & 31))] = sv[k];
        }
    }
    __syncthreads();

    phaseB_epilogue(smem_f, t, l, nb, Wt, b1, W2l, W2r, g, r);
}

// ---------------------------------------------------------------------------
// Paths B/C: fused layer-1 (B = fp16 gather, C = fp32).
// ---------------------------------------------------------------------------
template <bool HALFX>
__global__ __launch_bounds__(1024, 8) void layer1_kernel(
    const int* __restrict__ off, const int* __restrict__ col,
    const float* __restrict__ x, const __half* __restrict__ xh,
    const float* __restrict__ Wt, const float* __restrict__ b1,
    const float* __restrict__ W2l, const float* __restrict__ W2r,
    float* __restrict__ g, float* __restrict__ r)
{
    __shared__ float smem_f[256 * 64];

    const int t  = threadIdx.x;
    const int nb = blockIdx.x * 64;
    const int l  = t & 63;

    {
        const int n_loc = t >> 4;
        const int ft    = t & 15;
        const int fbase = ft * 8;
        const int n     = nb + n_loc;
        const bool valid = (n < NN);

        float a[8];
#pragma unroll
        for (int i = 0; i < 8; ++i) a[i] = 0.0f;

        int s0 = 0, s1 = 0;
        if (valid) { s0 = off[n]; s1 = off[n + 1]; }

        int i = s0;
        if (HALFX) {
            for (; i + 3 < s1; i += 4) {
                int c0 = clampN(col[i]);
                int c1 = clampN(col[i + 1]);
                int c2 = clampN(col[i + 2]);
                int c3 = clampN(col[i + 3]);
                uint4 v0 = *(const uint4*)(xh + (size_t)c0 * FIN + fbase);
                uint4 v1 = *(const uint4*)(xh + (size_t)c1 * FIN + fbase);
                uint4 v2 = *(const uint4*)(xh + (size_t)c2 * FIN + fbase);
                uint4 v3 = *(const uint4*)(xh + (size_t)c3 * FIN + fbase);
#pragma unroll
                for (int u = 0; u < 4; ++u) {
                    float2 f0 = __half22float2(__builtin_bit_cast(__half2, (&v0.x)[u]));
                    float2 f1 = __half22float2(__builtin_bit_cast(__half2, (&v1.x)[u]));
                    float2 f2 = __half22float2(__builtin_bit_cast(__half2, (&v2.x)[u]));
                    float2 f3 = __half22float2(__builtin_bit_cast(__half2, (&v3.x)[u]));
                    a[2 * u]     += (f0.x + f1.x) + (f2.x + f3.x);
                    a[2 * u + 1] += (f0.y + f1.y) + (f2.y + f3.y);
                }
            }
            for (; i < s1; ++i) {
                int c0 = clampN(col[i]);
                uint4 v0 = *(const uint4*)(xh + (size_t)c0 * FIN + fbase);
#pragma unroll
                for (int u = 0; u < 4; ++u) {
                    float2 f0 = __half22float2(__builtin_bit_cast(__half2, (&v0.x)[u]));
                    a[2 * u]     += f0.x;
                    a[2 * u + 1] += f0.y;
                }
            }
        } else {
            for (; i < s1; ++i) {
                int c0 = clampN(col[i]);
                const float4* p0 = (const float4*)(x + (size_t)c0 * FIN + fbase);
                float4 v00 = p0[0], v01 = p0[1];
                a[0] += v00.x; a[1] += v00.y; a[2] += v00.z; a[3] += v00.w;
                a[4] += v01.x; a[5] += v01.y; a[6] += v01.z; a[7] += v01.w;
            }
        }
        float ic = 1.0f / fmaxf((float)(s1 - s0), 1.0f);
#pragma unroll
        for (int k = 0; k < 8; ++k) {
            int f = fbase + k;
            smem_f[f * 64 + (n_loc ^ ((f >> 3) & 31))] = a[k] * ic;
        }
        const float4* sp = (const float4*)(x + (size_t)(valid ? n : 0) * FIN + fbase);
        float4 s0v = valid ? sp[0] : make_float4(0.f, 0.f, 0.f, 0.f);
        float4 s1v = valid ? sp[1] : make_float4(0.f, 0.f, 0.f, 0.f);
        float sv[8] = {s0v.x, s0v.y, s0v.z, s0v.w, s1v.x, s1v.y, s1v.z, s1v.w};
#pragma unroll
        for (int k = 0; k < 8; ++k) {
            int f = FIN + fbase + k;
            smem_f[f * 64 + (n_loc ^ ((f >> 3) & 31))] = sv[k];
        }
    }
    __syncthreads();

    phaseB_epilogue(smem_f, t, l, nb, Wt, b1, W2l, W2r, g, r);
}

// layer-2 mean via CSR gather of g, +b2, +lin_r, L2-normalize, log_softmax
__global__ __launch_bounds__(256) void finalize_kernel(
    const int* __restrict__ off, const int* __restrict__ col,
    const float* __restrict__ g, const float* __restrict__ r,
    const float* __restrict__ b2,
    float* __restrict__ out)
{
    int n = blockIdx.x * 256 + threadIdx.x;
    if (n >= NN) return;
    int s0 = off[n], s1 = off[n + 1];
    float z0 = 0.0f, z1 = 0.0f, y0b = 0.0f, y1b = 0.0f;
    int i = s0;
    for (; i + 1 < s1; i += 2) {
        int sa = clampN(col[i]);
        int sb = clampN(col[i + 1]);
        float2 va = *(const float2*)(g + 2 * (size_t)sa);
        float2 vb = *(const float2*)(g + 2 * (size_t)sb);
        z0 += va.x; z1 += va.y;
        y0b += vb.x; y1b += vb.y;
    }
    if (i < s1) {
        int sa = clampN(col[i]);
        float2 va = *(const float2*)(g + 2 * (size_t)sa);
        z0 += va.x; z1 += va.y;
    }
    z0 += y0b; z1 += y1b;
    float ic = 1.0f / fmaxf((float)(s1 - s0), 1.0f);
    z0 = z0 * ic + b2[0] + r[2 * (size_t)n];
    z1 = z1 * ic + b2[1] + r[2 * (size_t)n + 1];
    float d = 1.0f / fmaxf(sqrtf(z0 * z0 + z1 * z1), FEPS);
    float y0 = z0 * d, y1 = z1 * d;
    float m = fmaxf(y0, y1);
    float l = m + logf(__expf(y0 - m) + __expf(y1 - m));
    out[2 * (size_t)n]     = y0 - l;
    out[2 * (size_t)n + 1] = y1 - l;
}

// ---------------------------------------------------------------------------
extern "C" void kernel_launch(void* const* d_in, const int* in_sizes, int n_in,
                              void* d_out, int out_size, void* d_ws, size_t ws_size,
                              hipStream_t stream) {
    // setup_inputs order: x, edge_index, W1_l, b1, W1_r, W2_l, b2, W2_r
    const float* x   = (const float*)d_in[0];
    const int*   ei  = (const int*)d_in[1];
    const float* W1l = (const float*)d_in[2];
    const float* b1  = (const float*)d_in[3];
    const float* W1r = (const float*)d_in[4];
    const float* W2l = (const float*)d_in[5];
    const float* b2  = (const float*)d_in[6];
    const float* W2r = (const float*)d_in[7];

    const int nsb = (NN + 1023) / 1024;          // 98 scan blocks
    const int ncv = (NN * FIN / 8 + 255) / 256;  // convert blocks
    const int ecb = (NE + 255) / 256;            // edge blocks

    const size_t tailWords = (size_t)2 * NN + (NN + 1) + NE + 4 * NN + 128;
    const size_t needB = (size_t)256 * 256 * 4 + (size_t)NN * FIN * 2 +
                         tailWords * 4;
    const size_t needA = needB + (size_t)NN * FIN * 4;   // + fp32 agg

    // host-side constants: graph-safe
    bool pathA = (ws_size >= needA);
    bool pathB = !pathA && (ws_size >= needB);
    bool half  = pathA || pathB;

    char* p = (char*)d_ws;
    float* Wt = (float*)p;                p += (size_t)256 * 256 * 4;
    __half* xh = nullptr;
    if (half) { xh = (__half*)p;          p += (size_t)NN * FIN * 2; }
    float* agg = nullptr;
    if (pathA) { agg = (float*)p;         p += (size_t)NN * FIN * 4; }

    int*   cnt  = (int*)p;
    int*   cur  = cnt + NN;
    int*   off  = cur + NN;                      // NN+1
    int*   col  = off + NN + 1;                  // NE
    float* g    = (float*)(col + NE);            // NN*2
    float* r    = g + 2 * (size_t)NN;            // NN*2
    int*   bsum = (int*)(r + 2 * (size_t)NN);    // 128

    hipMemsetAsync(cnt, 0, 2 * (size_t)NN * sizeof(int), stream);

    int cv = half ? ncv : 0;
    setup_kernel<<<256 + cv + ecb, 256, 0, stream>>>(ei, x, W1l, W1r, Wt, xh,
                                                     cnt, cv);
    scan_a_kernel<<<nsb, 1024, 0, stream>>>(cnt, off, bsum);
    scan_b_kernel<<<1, 128, 0, stream>>>(bsum, off, nsb);
    scan_c_kernel<<<nsb, 1024, 0, stream>>>(bsum, off);
    fill_kernel<<<ecb, 256, 0, stream>>>(ei, off, cur, col);

    if (pathA) {
        gather_kernel<<<(NN * 16 + 255) / 256, 256, 0, stream>>>(off, col, xh,
                                                                 agg);
        gemm_kernel<<<(NN + 63) / 64, 1024, 0, stream>>>(agg, x, Wt, b1,
                                                         W2l, W2r, g, r);
    } else if (pathB) {
        layer1_kernel<true><<<(NN + 63) / 64, 1024, 0, stream>>>(
            off, col, x, xh, Wt, b1, W2l, W2r, g, r);
    } else {
        layer1_kernel<false><<<(NN + 63) / 64, 1024, 0, stream>>>(
            off, col, x, xh, Wt, b1, W2l, W2r, g, r);
    }
    finalize_kernel<<<(NN + 255) / 256, 256, 0, stream>>>(off, col, g, r, b2,
                                                          (float*)d_out);
}